// Round 3
// baseline (115.244 us; speedup 1.0000x reference)
//
#include <hip/hip_runtime.h>

// VectorQuantizer via split-precision bf16 MFMA + exact-rescan refinement.
// z [65536,192] f32, codebook [512,192] f32
// out: z_q [65536*192] f32 ++ indices [65536] (as float)

#define NROWS 65536
#define D     192
#define V     512
#define MT    128          // rows per block (4 waves x 32)
#define NV    64           // codebook entries per LDS chunk
#define MARGIN 5e-4f       // > rigorous split-error bound; gates exact rescan

typedef __attribute__((ext_vector_type(8)))  short short8;   // 8 bf16 (4 VGPR)
typedef __attribute__((ext_vector_type(16))) float f32x16;   // 32x32 C frag

__device__ __forceinline__ unsigned short f2bf(float x) {    // RNE f32->bf16
    unsigned u = __float_as_uint(x);
    u += 0x7FFFu + ((u >> 16) & 1u);
    return (unsigned short)(u >> 16);
}
__device__ __forceinline__ float bf2f(unsigned short h) {
    return __uint_as_float(((unsigned)h) << 16);
}

// ---------------- prepass: codebook -> bf16 hi/lo planes ----------------
__global__ void vq_prep_convert(const float* __restrict__ cb,
                                unsigned short* __restrict__ ehi,
                                unsigned short* __restrict__ elo) {
    int i = (blockIdx.x * 256 + threadIdx.x) * 4;   // 98304 elems total
    float4 v = *(const float4*)(cb + i);
    ushort4 h, l;
    h.x = f2bf(v.x); l.x = f2bf(v.x - bf2f(h.x));
    h.y = f2bf(v.y); l.y = f2bf(v.y - bf2f(h.y));
    h.z = f2bf(v.z); l.z = f2bf(v.z - bf2f(h.z));
    h.w = f2bf(v.w); l.w = f2bf(v.w - bf2f(h.w));
    *(ushort4*)(ehi + i) = h;
    *(ushort4*)(elo + i) = l;
}

// esq with the SAME 4-accumulator float4 order as the exact rescan path
__global__ void vq_prep_esq(const float* __restrict__ cb, float* __restrict__ esq) {
    int r = blockIdx.x * 256 + threadIdx.x;         // 512 rows
    const float4* p = (const float4*)(cb + (size_t)r * D);
    float4 s = make_float4(0.f, 0.f, 0.f, 0.f);
#pragma unroll
    for (int k = 0; k < D / 4; ++k) {
        float4 e = p[k];
        s.x = fmaf(e.x, e.x, s.x); s.y = fmaf(e.y, e.y, s.y);
        s.z = fmaf(e.z, e.z, s.z); s.w = fmaf(e.w, e.w, s.w);
    }
    esq[r] = (s.x + s.y) + (s.z + s.w);
}

// ------------- exact fp32 rescan (np-mirroring, wave-cooperative) -------------
__device__ __noinline__ int vq_rescan(const float* __restrict__ z,
                                      const float* __restrict__ cb,
                                      const float* __restrict__ esq,
                                      int row, int lane) {
    const float4* zp = (const float4*)(z + (size_t)row * D);
    float4 s = make_float4(0.f, 0.f, 0.f, 0.f);
    for (int k = 0; k < D / 4; ++k) {
        float4 a = zp[k];
        s.x = fmaf(a.x, a.x, s.x); s.y = fmaf(a.y, a.y, s.y);
        s.z = fmaf(a.z, a.z, s.z); s.w = fmaf(a.w, a.w, s.w);
    }
    float zsq = (s.x + s.y) + (s.z + s.w);
    float bd = 3.402823466e+38f; int bi = V;
    for (int it = 0; it < V / 64; ++it) {
        int e = lane + it * 64;                     // ascending per lane
        const float4* ep = (const float4*)(cb + (size_t)e * D);
        float4 a = make_float4(0.f, 0.f, 0.f, 0.f);
        for (int k = 0; k < D / 4; ++k) {
            float4 b = ep[k], zv = zp[k];
            a.x = fmaf(zv.x, b.x, a.x); a.y = fmaf(zv.y, b.y, a.y);
            a.z = fmaf(zv.z, b.z, a.z); a.w = fmaf(zv.w, b.w, a.w);
        }
        float dot = (a.x + a.y) + (a.z + a.w);
        float d = (zsq + esq[e]) - 2.f * dot;       // identical to passing r1 formula
        if (d < bd) { bd = d; bi = e; }
    }
    for (int m = 1; m < 64; m <<= 1) {              // lexicographic (d, idx) min
        float od = __shfl_xor(bd, m);
        int   oi = __shfl_xor(bi, m);
        if (od < bd || (od == bd && oi < bi)) { bd = od; bi = oi; }
    }
    return bi;
}

// ------------------------------ main kernel ------------------------------
__global__ __launch_bounds__(256, 2)
void vq_mfma_kernel(const float* __restrict__ z,
                    const float* __restrict__ cb,
                    const unsigned short* __restrict__ ehi,
                    const unsigned short* __restrict__ elo,
                    const float* __restrict__ esq,
                    float* __restrict__ zq,
                    float* __restrict__ idx_out) {
    __shared__ unsigned short lds_e[2][NV * D];     // hi/lo planes, XOR-swizzled
    __shared__ float lds_esq[NV];
    __shared__ int   lds_win[MT];

    const int tid  = threadIdx.x;
    const int wave = tid >> 6;
    const int lane = tid & 63;
    const int l31  = lane & 31;
    const int half = lane >> 5;

    const int rowblk = blockIdx.x * MT;
    const int myrow  = rowblk + wave * 32 + l31;

    // ---- prologue: z row -> 12 k-step A-frags, bf16 hi/lo ----
    short8 zhi[12], zlo[12];
    {
        const float* zr = z + (size_t)myrow * D + half * 8;
#pragma unroll
        for (int s = 0; s < 12; ++s) {
            float4 a = *(const float4*)(zr + s * 16);
            float4 b = *(const float4*)(zr + s * 16 + 4);
            float xs[8] = {a.x, a.y, a.z, a.w, b.x, b.y, b.z, b.w};
            short8 h, l;
#pragma unroll
            for (int j = 0; j < 8; ++j) {
                unsigned short hb = f2bf(xs[j]);
                h[j] = (short)hb;
                l[j] = (short)f2bf(xs[j] - bf2f(hb));
            }
            zhi[s] = h; zlo[s] = l;
        }
    }

    float v1q[16], v2q[16]; int i1q[16];
#pragma unroll
    for (int q = 0; q < 16; ++q) { v1q[q] = 3.402823466e+38f; v2q[q] = 3.402823466e+38f; i1q[q] = 0; }

    const int swz = (l31 & 7) << 4;
    const int rb0 = l31 * 384;

    for (int c = 0; c < V / NV; ++c) {
        const int n0 = c * NV;
        __syncthreads();                            // prior chunk reads done
        // stage: 2 planes x 64 rows x 24 cols of 16B = 3072 xfers / 256 thr
#pragma unroll
        for (int it = 0; it < 12; ++it) {
            int u = tid + it * 256;
            int p = (u >= 1536) ? 1 : 0;
            int u2 = u - p * 1536;
            int rowc = u2 / 24;
            int col  = u2 - rowc * 24;
            const unsigned short* srcp = p ? elo : ehi;
            const uint4* src = (const uint4*)(srcp + (size_t)(n0 + rowc) * D + col * 8);
            int dst = (rowc * 384 + col * 16) ^ ((rowc & 7) << 4);
            *(uint4*)((char*)&lds_e[p][0] + dst) = *src;
        }
        if (tid < NV) lds_esq[tid] = esq[n0 + tid];
        __syncthreads();

        f32x16 acc0, acc1;
#pragma unroll
        for (int q = 0; q < 16; ++q) { acc0[q] = 0.f; acc1[q] = 0.f; }

#pragma unroll
        for (int s = 0; s < 12; ++s) {
            int a0 = (rb0 + s * 32 + half * 16) ^ swz;
            const char* base0 = (const char*)&lds_e[0][0];
            const char* base1 = (const char*)&lds_e[1][0];
            short8 bh0 = *(const short8*)(base0 + a0);
            short8 bl0 = *(const short8*)(base1 + a0);
            short8 bh1 = *(const short8*)(base0 + a0 + 32 * 384);
            short8 bl1 = *(const short8*)(base1 + a0 + 32 * 384);
            acc0 = __builtin_amdgcn_mfma_f32_32x32x16_bf16(zhi[s], bh0, acc0, 0, 0, 0);
            acc0 = __builtin_amdgcn_mfma_f32_32x32x16_bf16(zlo[s], bh0, acc0, 0, 0, 0);
            acc0 = __builtin_amdgcn_mfma_f32_32x32x16_bf16(zhi[s], bl0, acc0, 0, 0, 0);
            acc1 = __builtin_amdgcn_mfma_f32_32x32x16_bf16(zhi[s], bh1, acc1, 0, 0, 0);
            acc1 = __builtin_amdgcn_mfma_f32_32x32x16_bf16(zlo[s], bh1, acc1, 0, 0, 0);
            acc1 = __builtin_amdgcn_mfma_f32_32x32x16_bf16(zhi[s], bl1, acc1, 0, 0, 0);
        }

        float e0 = lds_esq[l31], e1 = lds_esq[32 + l31];
#pragma unroll
        for (int q = 0; q < 16; ++q) {
            float d0 = fmaf(-2.f, acc0[q], e0);
            bool b0 = d0 < v1q[q];
            v2q[q] = fminf(b0 ? v1q[q] : d0, v2q[q]);
            i1q[q] = b0 ? (n0 + l31) : i1q[q];
            v1q[q] = b0 ? d0 : v1q[q];
            float d1 = fmaf(-2.f, acc1[q], e1);
            bool b1 = d1 < v1q[q];
            v2q[q] = fminf(b1 ? v1q[q] : d1, v2q[q]);
            i1q[q] = b1 ? (n0 + 32 + l31) : i1q[q];
            v1q[q] = b1 ? d1 : v1q[q];
        }
    }

    // ---- cross-lane top2 merge (within 32-lane half; masks 1..16) ----
#pragma unroll
    for (int q = 0; q < 16; ++q) {
#pragma unroll
        for (int m = 1; m <= 16; m <<= 1) {
            float ov1 = __shfl_xor(v1q[q], m);
            int   oi1 = __shfl_xor(i1q[q], m);
            float ov2 = __shfl_xor(v2q[q], m);
            bool take = (ov1 < v1q[q]) || ((ov1 == v1q[q]) && (oi1 < i1q[q]));
            float lose = take ? v1q[q] : ov1;
            v2q[q] = fminf(fminf(v2q[q], ov2), lose);
            v1q[q] = take ? ov1 : v1q[q];
            i1q[q] = take ? oi1 : i1q[q];
        }
    }
    if (l31 == 0) {
#pragma unroll
        for (int q = 0; q < 16; ++q) {
            int rloc = wave * 32 + (q & 3) + ((q >> 2) << 3) + half * 4;
            bool need = (v2q[q] - v1q[q]) <= MARGIN;
            lds_win[rloc] = i1q[q] | (need ? (int)0x80000000 : 0);
        }
    }
    __syncthreads();

    // ---- finalize: rescan rare ambiguous rows, gather z_q, write idx ----
    for (int rr = 0; rr < 32; ++rr) {
        int w = lds_win[wave * 32 + rr];            // broadcast, wave-uniform
        int idx = w & 0xffff;
        int row = rowblk + wave * 32 + rr;
        if (w < 0) idx = vq_rescan(z, cb, esq, row, lane);
        if (lane < 48) {
            *(float4*)(zq + (size_t)row * D + lane * 4) =
                *(const float4*)(cb + (size_t)idx * D + lane * 4);
        } else if (lane == 48) {
            idx_out[row] = (float)idx;
        }
    }
}

// --------- round-1 fallback (used only if ws is unexpectedly small) ---------
#define TV 32
#define FBLOCK 128
__global__ __launch_bounds__(FBLOCK, 2)
void vq_argmin_fallback(const float* __restrict__ z, const float* __restrict__ cb,
                        float* __restrict__ zq, float* __restrict__ idx_out) {
    __shared__ float lds_cb[TV * D];
    __shared__ float lds_esq[TV];
    const int row = blockIdx.x * FBLOCK + threadIdx.x;
    float4 zr[D / 4];
    const float4* zp = (const float4*)(z + (size_t)row * D);
    float4 s = make_float4(0.f, 0.f, 0.f, 0.f);
#pragma unroll
    for (int i = 0; i < D / 4; ++i) {
        zr[i] = zp[i];
        s.x = fmaf(zr[i].x, zr[i].x, s.x); s.y = fmaf(zr[i].y, zr[i].y, s.y);
        s.z = fmaf(zr[i].z, zr[i].z, s.z); s.w = fmaf(zr[i].w, zr[i].w, s.w);
    }
    const float zsq = (s.x + s.y) + (s.z + s.w);
    float best = 3.4e38f; int bidx = 0;
    for (int vt = 0; vt < V / TV; ++vt) {
        __syncthreads();
        const float4* cbp = (const float4*)(cb + (size_t)vt * TV * D);
        float4* l4 = (float4*)lds_cb;
#pragma unroll
        for (int i = 0; i < (TV * D / 4) / FBLOCK; ++i)
            l4[threadIdx.x + i * FBLOCK] = cbp[threadIdx.x + i * FBLOCK];
        __syncthreads();
        if (threadIdx.x < TV) {
            const float* e = lds_cb + threadIdx.x * D;
            float4 es = make_float4(0.f, 0.f, 0.f, 0.f);
#pragma unroll
            for (int k = 0; k < D; k += 4) {
                es.x = fmaf(e[k], e[k], es.x); es.y = fmaf(e[k+1], e[k+1], es.y);
                es.z = fmaf(e[k+2], e[k+2], es.z); es.w = fmaf(e[k+3], e[k+3], es.w);
            }
            lds_esq[threadIdx.x] = (es.x + es.y) + (es.z + es.w);
        }
        __syncthreads();
#pragma unroll 2
        for (int v = 0; v < TV; ++v) {
            const float4* e4 = (const float4*)(lds_cb + v * D);
            float4 a = make_float4(0.f, 0.f, 0.f, 0.f);
#pragma unroll
            for (int k = 0; k < D / 4; ++k) {
                float4 b = e4[k];
                a.x = fmaf(zr[k].x, b.x, a.x); a.y = fmaf(zr[k].y, b.y, a.y);
                a.z = fmaf(zr[k].z, b.z, a.z); a.w = fmaf(zr[k].w, b.w, a.w);
            }
            const float dot = (a.x + a.y) + (a.z + a.w);
            const float dist = (zsq + lds_esq[v]) - 2.f * dot;
            if (dist < best) { best = dist; bidx = vt * TV + v; }
        }
    }
    float4* zqp = (float4*)(zq + (size_t)row * D);
    const float4* bp = (const float4*)(cb + (size_t)bidx * D);
#pragma unroll
    for (int i = 0; i < D / 4; ++i) zqp[i] = bp[i];
    idx_out[row] = (float)bidx;
}

extern "C" void kernel_launch(void* const* d_in, const int* in_sizes, int n_in,
                              void* d_out, int out_size, void* d_ws, size_t ws_size,
                              hipStream_t stream) {
    const float* z  = (const float*)d_in[0];
    const float* cb = (const float*)d_in[1];
    float* zq      = (float*)d_out;
    float* idx_out = (float*)d_out + (size_t)NROWS * D;

    const size_t ehi_bytes = (size_t)V * D * 2;            // 196608
    const size_t need = ehi_bytes * 2 + V * sizeof(float); // + esq
    if (ws_size < need) {
        vq_argmin_fallback<<<NROWS / FBLOCK, FBLOCK, 0, stream>>>(z, cb, zq, idx_out);
        return;
    }
    unsigned short* ehi = (unsigned short*)d_ws;
    unsigned short* elo = ehi + (size_t)V * D;
    float* esq = (float*)((char*)d_ws + 2 * ehi_bytes);

    vq_prep_convert<<<(V * D / 4) / 256, 256, 0, stream>>>(cb, ehi, elo);
    vq_prep_esq<<<V / 256, 256, 0, stream>>>(cb, esq);
    vq_mfma_kernel<<<NROWS / MT, 256, 0, stream>>>(z, cb, ehi, elo, esq, zq, idx_out);
}

// Round 4
// 108.227 us; speedup vs baseline: 1.0648x; 1.0648x over previous
//
#include <hip/hip_runtime.h>

// VectorQuantizer: split-precision bf16 MFMA, pre-fragmented codebook in global
// (no LDS, no barriers), 1-wave blocks, ballot-gated exact rescan.
// z [65536,192] f32, codebook [512,192] f32
// out: z_q [65536*192] f32 ++ indices [65536] (as float)

#define NROWS 65536
#define D     192
#define V     512
#define MARGIN 5e-4f

typedef __attribute__((ext_vector_type(8)))  short short8;   // 8 bf16 (4 VGPR)
typedef __attribute__((ext_vector_type(16))) float f32x16;   // 32x32 C frag

__device__ __forceinline__ unsigned short f2bf(float x) {    // RNE f32->bf16
    unsigned u = __float_as_uint(x);
    u += 0x7FFFu + ((u >> 16) & 1u);
    return (unsigned short)(u >> 16);
}
__device__ __forceinline__ float bf2f(unsigned short h) {
    return __uint_as_float(((unsigned)h) << 16);
}

// ---- prepass: codebook -> B-frag-ordered bf16 hi/lo planes + esq ----
// Unit u (16B, one lane's frag slice): u = ((c*12 + s)*4 + cp)*64 + lane
//   cp: 0=hi col-block0, 1=lo cb0, 2=hi cb1, 3=lo cb1
//   col = c*64 + (cp>>1)*32 + (lane&31), k = s*16 + (lane>>5)*8 + j
__global__ void vq_prep(const float* __restrict__ cb,
                        short8* __restrict__ F,
                        float* __restrict__ esq) {
    int u = blockIdx.x * 256 + threadIdx.x;        // 0..24575
    int lane = u & 63;
    int cp   = (u >> 6) & 3;
    int t    = u >> 8;                              // 0..95 = c*12+s
    int c = t / 12, s = t - c * 12;
    int col  = c * 64 + (cp >> 1) * 32 + (lane & 31);
    int koff = s * 16 + (lane >> 5) * 8;
    const float* src = cb + (size_t)col * D + koff;
    float4 a = *(const float4*)(src);
    float4 b = *(const float4*)(src + 4);
    float xs[8] = {a.x, a.y, a.z, a.w, b.x, b.y, b.z, b.w};
    short8 o;
    if ((cp & 1) == 0) {
#pragma unroll
        for (int j = 0; j < 8; ++j) o[j] = (short)f2bf(xs[j]);
    } else {
#pragma unroll
        for (int j = 0; j < 8; ++j) {
            unsigned short hb = f2bf(xs[j]);
            o[j] = (short)f2bf(xs[j] - bf2f(hb));
        }
    }
    F[u] = o;

    if (u < V) {                                    // fused esq (same order as rescan)
        const float4* p = (const float4*)(cb + (size_t)u * D);
        float4 es = make_float4(0.f, 0.f, 0.f, 0.f);
#pragma unroll
        for (int k = 0; k < D / 4; ++k) {
            float4 e = p[k];
            es.x = fmaf(e.x, e.x, es.x); es.y = fmaf(e.y, e.y, es.y);
            es.z = fmaf(e.z, e.z, es.z); es.w = fmaf(e.w, e.w, es.w);
        }
        esq[u] = (es.x + es.y) + (es.z + es.w);
    }
}

// ---- exact fp32 rescan (bit-identical to the round-1 verified path) ----
__device__ __noinline__ int vq_rescan(const float* __restrict__ z,
                                      const float* __restrict__ cb,
                                      const float* __restrict__ esq,
                                      int row, int lane) {
    const float4* zp = (const float4*)(z + (size_t)row * D);
    float4 s = make_float4(0.f, 0.f, 0.f, 0.f);
    for (int k = 0; k < D / 4; ++k) {
        float4 a = zp[k];
        s.x = fmaf(a.x, a.x, s.x); s.y = fmaf(a.y, a.y, s.y);
        s.z = fmaf(a.z, a.z, s.z); s.w = fmaf(a.w, a.w, s.w);
    }
    float zsq = (s.x + s.y) + (s.z + s.w);
    float bd = 3.402823466e+38f; int bi = V;
    for (int it = 0; it < V / 64; ++it) {
        int e = lane + it * 64;
        const float4* ep = (const float4*)(cb + (size_t)e * D);
        float4 a = make_float4(0.f, 0.f, 0.f, 0.f);
        for (int k = 0; k < D / 4; ++k) {
            float4 b = ep[k], zv = zp[k];
            a.x = fmaf(zv.x, b.x, a.x); a.y = fmaf(zv.y, b.y, a.y);
            a.z = fmaf(zv.z, b.z, a.z); a.w = fmaf(zv.w, b.w, a.w);
        }
        float dot = (a.x + a.y) + (a.z + a.w);
        float d = (zsq + esq[e]) - 2.f * dot;
        if (d < bd) { bd = d; bi = e; }
    }
    for (int m = 1; m < 64; m <<= 1) {
        float od = __shfl_xor(bd, m);
        int   oi = __shfl_xor(bi, m);
        if (od < bd || (od == bd && oi < bi)) { bd = od; bi = oi; }
    }
    return bi;
}

// ------------------------------ main kernel ------------------------------
__global__ __launch_bounds__(64, 2)
void vq_main(const float* __restrict__ z,
             const float* __restrict__ cb,
             const short8* __restrict__ F,
             const float* __restrict__ esq,
             float* __restrict__ zq,
             float* __restrict__ idx_out) {
    const int lane = threadIdx.x;
    const int l31  = lane & 31;
    const int half = lane >> 5;
    const int rowbase = blockIdx.x * 32;
    const int myrow   = rowbase + l31;

    // ---- A prologue: z row -> 12 k-step hi/lo frags ----
    short8 zhi[12], zlo[12];
    {
        const float* zr = z + (size_t)myrow * D + half * 8;
#pragma unroll
        for (int s = 0; s < 12; ++s) {
            float4 a = *(const float4*)(zr + s * 16);
            float4 b = *(const float4*)(zr + s * 16 + 4);
            float xs[8] = {a.x, a.y, a.z, a.w, b.x, b.y, b.z, b.w};
            short8 h, l;
#pragma unroll
            for (int j = 0; j < 8; ++j) {
                unsigned short hb = f2bf(xs[j]);
                h[j] = (short)hb;
                l[j] = (short)f2bf(xs[j] - bf2f(hb));
            }
            zhi[s] = h; zlo[s] = l;
        }
    }

    float v1q[16], v2q[16]; int i1q[16];
#pragma unroll
    for (int q = 0; q < 16; ++q) { v1q[q] = 3.402823466e+38f; v2q[q] = 3.402823466e+38f; i1q[q] = 0; }

    // ---- 3-deep B-frag register ring, prefetch t=0,1,2 ----
    const short8* Fl = F + lane;                    // unit stride = 64 short8
    short8 bf0[4], bf1[4], bf2[4];
#pragma unroll
    for (int cp = 0; cp < 4; ++cp) bf0[cp] = Fl[(0 * 4 + cp) * 64];
#pragma unroll
    for (int cp = 0; cp < 4; ++cp) bf1[cp] = Fl[(1 * 4 + cp) * 64];
#pragma unroll
    for (int cp = 0; cp < 4; ++cp) bf2[cp] = Fl[(2 * 4 + cp) * 64];

#define STEP(S, BUF)                                                              \
    acc0 = __builtin_amdgcn_mfma_f32_32x32x16_bf16(zhi[S], BUF[0], acc0, 0, 0, 0);\
    acc0 = __builtin_amdgcn_mfma_f32_32x32x16_bf16(zlo[S], BUF[0], acc0, 0, 0, 0);\
    acc0 = __builtin_amdgcn_mfma_f32_32x32x16_bf16(zhi[S], BUF[1], acc0, 0, 0, 0);\
    acc1 = __builtin_amdgcn_mfma_f32_32x32x16_bf16(zhi[S], BUF[2], acc1, 0, 0, 0);\
    acc1 = __builtin_amdgcn_mfma_f32_32x32x16_bf16(zlo[S], BUF[2], acc1, 0, 0, 0);\
    acc1 = __builtin_amdgcn_mfma_f32_32x32x16_bf16(zhi[S], BUF[3], acc1, 0, 0, 0);\
    {                                                                             \
        int t3 = c * 12 + (S) + 3;                                                \
        if (t3 < 96) {                                                            \
            BUF[0] = Fl[(t3 * 4 + 0) * 64]; BUF[1] = Fl[(t3 * 4 + 1) * 64];       \
            BUF[2] = Fl[(t3 * 4 + 2) * 64]; BUF[3] = Fl[(t3 * 4 + 3) * 64];       \
        }                                                                         \
    }

    for (int c = 0; c < 8; ++c) {
        const int n0 = c * 64;
        float e0 = esq[n0 + l31];
        float e1 = esq[n0 + 32 + l31];
        f32x16 acc0, acc1;
#pragma unroll
        for (int q = 0; q < 16; ++q) { acc0[q] = 0.f; acc1[q] = 0.f; }

        STEP(0, bf0)  STEP(1, bf1)  STEP(2, bf2)
        STEP(3, bf0)  STEP(4, bf1)  STEP(5, bf2)
        STEP(6, bf0)  STEP(7, bf1)  STEP(8, bf2)
        STEP(9, bf0)  STEP(10, bf1) STEP(11, bf2)

#pragma unroll
        for (int q = 0; q < 16; ++q) {
            float d0 = fmaf(-2.f, acc0[q], e0);
            bool b0 = d0 < v1q[q];
            v2q[q] = fminf(b0 ? v1q[q] : d0, v2q[q]);
            i1q[q] = b0 ? (n0 + l31) : i1q[q];
            v1q[q] = b0 ? d0 : v1q[q];
            float d1 = fmaf(-2.f, acc1[q], e1);
            bool b1 = d1 < v1q[q];
            v2q[q] = fminf(b1 ? v1q[q] : d1, v2q[q]);
            i1q[q] = b1 ? (n0 + 32 + l31) : i1q[q];
            v1q[q] = b1 ? d1 : v1q[q];
        }
    }
#undef STEP

    // ---- cross-lane top2 merge within each 32-lane half ----
#pragma unroll
    for (int q = 0; q < 16; ++q) {
#pragma unroll
        for (int m = 1; m <= 16; m <<= 1) {
            float ov1 = __shfl_xor(v1q[q], m);
            int   oi1 = __shfl_xor(i1q[q], m);
            float ov2 = __shfl_xor(v2q[q], m);
            bool take = (ov1 < v1q[q]) || ((ov1 == v1q[q]) && (oi1 < i1q[q]));
            float lose = take ? v1q[q] : ov1;
            v2q[q] = fminf(fminf(v2q[q], ov2), lose);
            v1q[q] = take ? ov1 : v1q[q];
            i1q[q] = take ? oi1 : i1q[q];
        }
    }

    // ---- epilogue: rare exact rescan + wave-cooperative gather + idx ----
#pragma unroll
    for (int q = 0; q < 16; ++q) {
        bool nd = (v2q[q] - v1q[q]) <= MARGIN;
        unsigned long long bm = __ballot(nd);
        int idx = i1q[q];
        const int r0 = rowbase + (q & 3) + 8 * (q >> 2);
        if (bm & 1ull) {                      // half 0 ambiguous (uniform)
            int ridx = vq_rescan(z, cb, esq, r0, lane);
            if (half == 0) idx = ridx;
        }
        if ((bm >> 32) & 1ull) {              // half 1 ambiguous (uniform)
            int ridx = vq_rescan(z, cb, esq, r0 + 4, lane);
            if (half == 1) idx = ridx;
        }
        const int row = r0 + half * 4;
        const float4* srcv = (const float4*)(cb + (size_t)idx * D);
        float4* dstv = (float4*)(zq + (size_t)row * D);
        dstv[l31] = srcv[l31];
        if (l31 < 16) dstv[32 + l31] = srcv[32 + l31];
        if (l31 == 0) idx_out[row] = (float)idx;
    }
}

// --------- round-1 fallback (only if ws is unexpectedly small) ---------
#define TV 32
#define FBLOCK 128
__global__ __launch_bounds__(FBLOCK, 2)
void vq_argmin_fallback(const float* __restrict__ z, const float* __restrict__ cb,
                        float* __restrict__ zq, float* __restrict__ idx_out) {
    __shared__ float lds_cb[TV * D];
    __shared__ float lds_esq[TV];
    const int row = blockIdx.x * FBLOCK + threadIdx.x;
    float4 zr[D / 4];
    const float4* zp = (const float4*)(z + (size_t)row * D);
    float4 s = make_float4(0.f, 0.f, 0.f, 0.f);
#pragma unroll
    for (int i = 0; i < D / 4; ++i) {
        zr[i] = zp[i];
        s.x = fmaf(zr[i].x, zr[i].x, s.x); s.y = fmaf(zr[i].y, zr[i].y, s.y);
        s.z = fmaf(zr[i].z, zr[i].z, s.z); s.w = fmaf(zr[i].w, zr[i].w, s.w);
    }
    const float zsq = (s.x + s.y) + (s.z + s.w);
    float best = 3.4e38f; int bidx = 0;
    for (int vt = 0; vt < V / TV; ++vt) {
        __syncthreads();
        const float4* cbp = (const float4*)(cb + (size_t)vt * TV * D);
        float4* l4 = (float4*)lds_cb;
#pragma unroll
        for (int i = 0; i < (TV * D / 4) / FBLOCK; ++i)
            l4[threadIdx.x + i * FBLOCK] = cbp[threadIdx.x + i * FBLOCK];
        __syncthreads();
        if (threadIdx.x < TV) {
            const float* e = lds_cb + threadIdx.x * D;
            float4 es = make_float4(0.f, 0.f, 0.f, 0.f);
#pragma unroll
            for (int k = 0; k < D; k += 4) {
                es.x = fmaf(e[k], e[k], es.x); es.y = fmaf(e[k+1], e[k+1], es.y);
                es.z = fmaf(e[k+2], e[k+2], es.z); es.w = fmaf(e[k+3], e[k+3], es.w);
            }
            lds_esq[threadIdx.x] = (es.x + es.y) + (es.z + es.w);
        }
        __syncthreads();
#pragma unroll 2
        for (int v = 0; v < TV; ++v) {
            const float4* e4 = (const float4*)(lds_cb + v * D);
            float4 a = make_float4(0.f, 0.f, 0.f, 0.f);
#pragma unroll
            for (int k = 0; k < D / 4; ++k) {
                float4 b = e4[k];
                a.x = fmaf(zr[k].x, b.x, a.x); a.y = fmaf(zr[k].y, b.y, a.y);
                a.z = fmaf(zr[k].z, b.z, a.z); a.w = fmaf(zr[k].w, b.w, a.w);
            }
            const float dot = (a.x + a.y) + (a.z + a.w);
            const float dist = (zsq + lds_esq[v]) - 2.f * dot;
            if (dist < best) { best = dist; bidx = vt * TV + v; }
        }
    }
    float4* zqp = (float4*)(zq + (size_t)row * D);
    const float4* bp = (const float4*)(cb + (size_t)bidx * D);
#pragma unroll
    for (int i = 0; i < D / 4; ++i) zqp[i] = bp[i];
    idx_out[row] = (float)bidx;
}

extern "C" void kernel_launch(void* const* d_in, const int* in_sizes, int n_in,
                              void* d_out, int out_size, void* d_ws, size_t ws_size,
                              hipStream_t stream) {
    const float* z  = (const float*)d_in[0];
    const float* cb = (const float*)d_in[1];
    float* zq      = (float*)d_out;
    float* idx_out = (float*)d_out + (size_t)NROWS * D;

    const size_t f_bytes = (size_t)96 * 4 * 64 * 16;        // 393216
    const size_t need = f_bytes + V * sizeof(float);
    if (ws_size < need) {
        vq_argmin_fallback<<<NROWS / FBLOCK, FBLOCK, 0, stream>>>(z, cb, zq, idx_out);
        return;
    }
    short8* F  = (short8*)d_ws;
    float* esq = (float*)((char*)d_ws + f_bytes);

    vq_prep<<<96, 256, 0, stream>>>(cb, F, esq);
    vq_main<<<NROWS / 32, 64, 0, stream>>>(z, cb, F, esq, zq, idx_out);
}

// Round 5
// 99.063 us; speedup vs baseline: 1.1633x; 1.0925x over previous
//
#include <hip/hip_runtime.h>

// VectorQuantizer: split-precision bf16 MFMA (16x16x32), 4-wave blocks,
// LDS-shared frag-linear codebook chunks, counted-vmcnt double buffer.
// z [65536,192] f32, codebook [512,192] f32
// out: z_q [65536*192] f32 ++ indices [65536] (as float)

#define NROWS 65536
#define D     192
#define V     512
#define MARGIN 5e-4f
#define NCHUNK 32                 // V / 16 entries per chunk
#define CHUNK_BYTES 12288         // 16 cols * 192 k * 2B * 2 planes

typedef __attribute__((ext_vector_type(8))) short short8;  // 8 bf16
typedef __attribute__((ext_vector_type(4))) float f32x4;   // 16x16 C frag

__device__ __forceinline__ unsigned short f2bf(float x) {   // RNE f32->bf16
    unsigned u = __float_as_uint(x);
    u += 0x7FFFu + ((u >> 16) & 1u);
    return (unsigned short)(u >> 16);
}
__device__ __forceinline__ float bf2f(unsigned short h) {
    return __uint_as_float(((unsigned)h) << 16);
}

// ---- prepass: codebook -> frag-linear bf16 hi/lo F + esq ----
// frag f = (c*6 + s)*2 + p ; F[f*64 + lane] = 8 bf16 of
//   col = c*16 + (lane&15), k = s*32 + (lane>>4)*8 + j
__global__ void vq_prep(const float* __restrict__ cb,
                        short8* __restrict__ F,
                        float* __restrict__ esq) {
    int u = blockIdx.x * 256 + threadIdx.x;       // 0..24575
    int lane = u & 63;
    int f = u >> 6;                                // 0..383
    int p = f & 1;
    int t = f >> 1;                                // c*6+s
    int c = t / 6, s = t - c * 6;
    int col  = c * 16 + (lane & 15);
    int koff = s * 32 + (lane >> 4) * 8;
    const float* src = cb + (size_t)col * D + koff;
    float4 a = *(const float4*)(src);
    float4 b = *(const float4*)(src + 4);
    float xs[8] = {a.x, a.y, a.z, a.w, b.x, b.y, b.z, b.w};
    short8 o;
    if (p == 0) {
#pragma unroll
        for (int j = 0; j < 8; ++j) o[j] = (short)f2bf(xs[j]);
    } else {
#pragma unroll
        for (int j = 0; j < 8; ++j) {
            unsigned short hb = f2bf(xs[j]);
            o[j] = (short)f2bf(xs[j] - bf2f(hb));
        }
    }
    F[u] = o;

    if (u < V) {                                   // esq, same order as rescan
        const float4* pp = (const float4*)(cb + (size_t)u * D);
        float4 es = make_float4(0.f, 0.f, 0.f, 0.f);
#pragma unroll
        for (int k = 0; k < D / 4; ++k) {
            float4 e = pp[k];
            es.x = fmaf(e.x, e.x, es.x); es.y = fmaf(e.y, e.y, es.y);
            es.z = fmaf(e.z, e.z, es.z); es.w = fmaf(e.w, e.w, es.w);
        }
        esq[u] = (es.x + es.y) + (es.z + es.w);
    }
}

// ---- exact fp32 rescan (round-1-verified bit-exact formula) ----
__device__ __noinline__ int vq_rescan(const float* __restrict__ z,
                                      const float* __restrict__ cb,
                                      const float* __restrict__ esq,
                                      int row, int lane) {
    const float4* zp = (const float4*)(z + (size_t)row * D);
    float4 s = make_float4(0.f, 0.f, 0.f, 0.f);
    for (int k = 0; k < D / 4; ++k) {
        float4 a = zp[k];
        s.x = fmaf(a.x, a.x, s.x); s.y = fmaf(a.y, a.y, s.y);
        s.z = fmaf(a.z, a.z, s.z); s.w = fmaf(a.w, a.w, s.w);
    }
    float zsq = (s.x + s.y) + (s.z + s.w);
    float bd = 3.402823466e+38f; int bi = V;
    for (int it = 0; it < V / 64; ++it) {
        int e = lane + it * 64;
        const float4* ep = (const float4*)(cb + (size_t)e * D);
        float4 a = make_float4(0.f, 0.f, 0.f, 0.f);
        for (int k = 0; k < D / 4; ++k) {
            float4 b = ep[k], zv = zp[k];
            a.x = fmaf(zv.x, b.x, a.x); a.y = fmaf(zv.y, b.y, a.y);
            a.z = fmaf(zv.z, b.z, a.z); a.w = fmaf(zv.w, b.w, a.w);
        }
        float dot = (a.x + a.y) + (a.z + a.w);
        float d = (zsq + esq[e]) - 2.f * dot;
        if (d < bd) { bd = d; bi = e; }
    }
    for (int m = 1; m < 64; m <<= 1) {
        float od = __shfl_xor(bd, m);
        int   oi = __shfl_xor(bi, m);
        if (od < bd || (od == bd && oi < bi)) { bd = od; bi = oi; }
    }
    return bi;
}

// ------------------------------ main kernel ------------------------------
__global__ __launch_bounds__(256, 4)
void vq_main(const float* __restrict__ z,
             const float* __restrict__ cb,
             const char* __restrict__ F,
             const float* __restrict__ esq,
             float* __restrict__ zq,
             float* __restrict__ idx_out) {
    __shared__ __align__(16) char lds_buf[2][CHUNK_BYTES];
    __shared__ float lds_esq[V];

    const int tid  = threadIdx.x;
    const int wave = tid >> 6;
    const int lane = tid & 63;
    const int n15  = lane & 15;
    const int g    = lane >> 4;

    const int rowblk = blockIdx.x * 64;
    const int wrow   = rowblk + wave * 16;
    const int myrow  = wrow + n15;                // A row this lane loads

    // esq -> LDS (waves 0,1)
    if (tid < 128)
        ((float4*)lds_esq)[tid] = ((const float4*)esq)[tid];

    // ---- A prologue: z row -> 6 k-step hi/lo frags ----
    short8 zhi[6], zlo[6];
    {
        const float* zr = z + (size_t)myrow * D + g * 8;
#pragma unroll
        for (int s = 0; s < 6; ++s) {
            float4 a = *(const float4*)(zr + s * 32);
            float4 b = *(const float4*)(zr + s * 32 + 4);
            float xs[8] = {a.x, a.y, a.z, a.w, b.x, b.y, b.z, b.w};
            short8 h, l;
#pragma unroll
            for (int j = 0; j < 8; ++j) {
                unsigned short hb = f2bf(xs[j]);
                h[j] = (short)hb;
                l[j] = (short)f2bf(xs[j] - bf2f(hb));
            }
            zhi[s] = h; zlo[s] = l;
        }
    }

    float v1[4], v2[4]; int i1[4];
#pragma unroll
    for (int r = 0; r < 4; ++r) { v1[r] = 3.402823466e+38f; v2[r] = 3.402823466e+38f; i1[r] = 0; }

#define STAGE(CC, BUF)                                                          \
    {                                                                           \
        const char* gsrc = F + (size_t)(CC) * CHUNK_BYTES + wave * 1024 + lane * 16; \
        char* ldst = &lds_buf[BUF][0] + wave * 1024;                            \
        _Pragma("unroll")                                                       \
        for (int it = 0; it < 3; ++it)                                          \
            __builtin_amdgcn_global_load_lds(                                   \
                (const __attribute__((address_space(1))) void*)(gsrc + it * 4096), \
                (__attribute__((address_space(3))) void*)(ldst + it * 4096),    \
                16, 0, 0);                                                      \
    }

    STAGE(0, 0);
    asm volatile("s_waitcnt lgkmcnt(0)" ::: "memory");   // esq ds_write drained

    for (int c = 0; c < NCHUNK; ++c) {
        const int cur = c & 1;
        if (c + 1 < NCHUNK) {
            STAGE(c + 1, cur ^ 1);                       // prefetch next chunk
            asm volatile("s_waitcnt vmcnt(3)" ::: "memory");  // chunk c staged
        } else {
            asm volatile("s_waitcnt vmcnt(0)" ::: "memory");
        }
        __builtin_amdgcn_s_barrier();                    // A: buf[cur] ready

        const char* B = &lds_buf[cur][0];
        f32x4 cA = {0.f, 0.f, 0.f, 0.f};
        f32x4 cB = {0.f, 0.f, 0.f, 0.f};
        f32x4 cC = {0.f, 0.f, 0.f, 0.f};
#pragma unroll
        for (int s = 0; s < 6; ++s) {
            short8 bh = *(const short8*)(B + (s * 2 + 0) * 1024 + lane * 16);
            short8 bl = *(const short8*)(B + (s * 2 + 1) * 1024 + lane * 16);
            cA = __builtin_amdgcn_mfma_f32_16x16x32_bf16(zhi[s], bh, cA, 0, 0, 0);
            cB = __builtin_amdgcn_mfma_f32_16x16x32_bf16(zlo[s], bh, cB, 0, 0, 0);
            cC = __builtin_amdgcn_mfma_f32_16x16x32_bf16(zhi[s], bl, cC, 0, 0, 0);
        }

        const float e = lds_esq[c * 16 + n15];
        const int idx = c * 16 + n15;
#pragma unroll
        for (int r = 0; r < 4; ++r) {
            float dot = (cA[r] + cB[r]) + cC[r];
            float d = fmaf(-2.f, dot, e);
            bool b = d < v1[r];
            v2[r] = fminf(b ? v1[r] : d, v2[r]);
            i1[r] = b ? idx : i1[r];
            v1[r] = b ? d : v1[r];
        }

        asm volatile("s_waitcnt lgkmcnt(0)" ::: "memory");
        __builtin_amdgcn_s_barrier();                    // B: reads of buf[cur] done
    }
#undef STAGE

    // ---- top2 merge across the 16 lanes of each group (masks 1,2,4,8) ----
#pragma unroll
    for (int r = 0; r < 4; ++r) {
#pragma unroll
        for (int m = 1; m <= 8; m <<= 1) {
            float ov1 = __shfl_xor(v1[r], m);
            int   oi1 = __shfl_xor(i1[r], m);
            float ov2 = __shfl_xor(v2[r], m);
            bool take = (ov1 < v1[r]) || ((ov1 == v1[r]) && (oi1 < i1[r]));
            float lose = take ? v1[r] : ov1;
            v2[r] = fminf(fminf(v2[r], ov2), lose);
            v1[r] = take ? ov1 : v1[r];
            i1[r] = take ? oi1 : i1[r];
        }
    }

    // ---- epilogue: rare exact rescan + gather + idx ----
#pragma unroll
    for (int r = 0; r < 4; ++r) {
        bool need = (v2[r] - v1[r]) <= MARGIN;
        unsigned long long bm = __ballot(need);
        int idx = i1[r];
        if (bm) {                                        // uniform, rare
            for (int gg = 0; gg < 4; ++gg) {
                if ((bm >> (gg * 16)) & 1ull) {
                    int ridx = vq_rescan(z, cb, esq, wrow + gg * 4 + r, lane);
                    if (g == gg) idx = ridx;
                }
            }
        }
        const int row = wrow + g * 4 + r;
        const float4* srcv = (const float4*)(cb + (size_t)idx * D);
        float4* dstv = (float4*)(zq + (size_t)row * D);
        dstv[n15]      = srcv[n15];
        dstv[n15 + 16] = srcv[n15 + 16];
        dstv[n15 + 32] = srcv[n15 + 32];
        if (n15 == 0) idx_out[row] = (float)idx;
    }
}

// --------- round-1 fallback (only if ws is unexpectedly small) ---------
#define TV 32
#define FBLOCK 128
__global__ __launch_bounds__(FBLOCK, 2)
void vq_argmin_fallback(const float* __restrict__ z, const float* __restrict__ cb,
                        float* __restrict__ zq, float* __restrict__ idx_out) {
    __shared__ float lds_cb[TV * D];
    __shared__ float lds_esq2[TV];
    const int row = blockIdx.x * FBLOCK + threadIdx.x;
    float4 zr[D / 4];
    const float4* zp = (const float4*)(z + (size_t)row * D);
    float4 s = make_float4(0.f, 0.f, 0.f, 0.f);
#pragma unroll
    for (int i = 0; i < D / 4; ++i) {
        zr[i] = zp[i];
        s.x = fmaf(zr[i].x, zr[i].x, s.x); s.y = fmaf(zr[i].y, zr[i].y, s.y);
        s.z = fmaf(zr[i].z, zr[i].z, s.z); s.w = fmaf(zr[i].w, zr[i].w, s.w);
    }
    const float zsq = (s.x + s.y) + (s.z + s.w);
    float best = 3.4e38f; int bidx = 0;
    for (int vt = 0; vt < V / TV; ++vt) {
        __syncthreads();
        const float4* cbp = (const float4*)(cb + (size_t)vt * TV * D);
        float4* l4 = (float4*)lds_cb;
#pragma unroll
        for (int i = 0; i < (TV * D / 4) / FBLOCK; ++i)
            l4[threadIdx.x + i * FBLOCK] = cbp[threadIdx.x + i * FBLOCK];
        __syncthreads();
        if (threadIdx.x < TV) {
            const float* e = lds_cb + threadIdx.x * D;
            float4 es = make_float4(0.f, 0.f, 0.f, 0.f);
#pragma unroll
            for (int k = 0; k < D; k += 4) {
                es.x = fmaf(e[k], e[k], es.x); es.y = fmaf(e[k+1], e[k+1], es.y);
                es.z = fmaf(e[k+2], e[k+2], es.z); es.w = fmaf(e[k+3], e[k+3], es.w);
            }
            lds_esq2[threadIdx.x] = (es.x + es.y) + (es.z + es.w);
        }
        __syncthreads();
#pragma unroll 2
        for (int v = 0; v < TV; ++v) {
            const float4* e4 = (const float4*)(lds_cb + v * D);
            float4 a = make_float4(0.f, 0.f, 0.f, 0.f);
#pragma unroll
            for (int k = 0; k < D / 4; ++k) {
                float4 b = e4[k];
                a.x = fmaf(zr[k].x, b.x, a.x); a.y = fmaf(zr[k].y, b.y, a.y);
                a.z = fmaf(zr[k].z, b.z, a.z); a.w = fmaf(zr[k].w, b.w, a.w);
            }
            const float dot = (a.x + a.y) + (a.z + a.w);
            const float dist = (zsq + lds_esq2[v]) - 2.f * dot;
            if (dist < best) { best = dist; bidx = vt * TV + v; }
        }
    }
    float4* zqp = (float4*)(zq + (size_t)row * D);
    const float4* bp = (const float4*)(cb + (size_t)bidx * D);
#pragma unroll
    for (int i = 0; i < D / 4; ++i) zqp[i] = bp[i];
    idx_out[row] = (float)bidx;
}

extern "C" void kernel_launch(void* const* d_in, const int* in_sizes, int n_in,
                              void* d_out, int out_size, void* d_ws, size_t ws_size,
                              hipStream_t stream) {
    const float* z  = (const float*)d_in[0];
    const float* cb = (const float*)d_in[1];
    float* zq      = (float*)d_out;
    float* idx_out = (float*)d_out + (size_t)NROWS * D;

    const size_t f_bytes = (size_t)384 * 1024;              // 384 frags x 1KB
    const size_t need = f_bytes + V * sizeof(float);
    if (ws_size < need) {
        vq_argmin_fallback<<<NROWS / FBLOCK, FBLOCK, 0, stream>>>(z, cb, zq, idx_out);
        return;
    }
    short8* F  = (short8*)d_ws;
    float* esq = (float*)((char*)d_ws + f_bytes);

    vq_prep<<<96, 256, 0, stream>>>(cb, F, esq);
    vq_main<<<NROWS / 64, 256, 0, stream>>>(z, cb, (const char*)F, esq, zq, idx_out);
}